// Round 1
// baseline (1911.169 us; speedup 1.0000x reference)
//
#include <hip/hip_runtime.h>
#include <cstddef>

// VGG-16 forward, batch=1, fp32. Strategy:
//  - conv3x3: block = 256 thr = 4 co-groups x 64 thr; tile 16x16 pixels,
//    each thread computes 2x2 pixels x 8 output channels (32 f32 acc).
//    Inputs (18x18 halo tile) + weights (32co x 9, padded to 12) staged in
//    double-buffered LDS; global->reg->LDS software pipeline, ONE barrier
//    per 2-ci step. K(ci)-split S for small layers keeps grid >= 512 blocks;
//    partials reduced (+ReLU, +optional fused maxpool) in a second pass.
//  - maxpool fused into conv epilogue for layers 2/4 (thread owns aligned 2x2).
//  - FC = row-per-block GEMV, float4 streaming, wave64 shuffle reduce.

#define TILE 16
#define COB  32

template<bool PARTIAL, bool POOL>
__global__ __launch_bounds__(256)
void conv3x3_k(const float* __restrict__ in, const float* __restrict__ wt,
               float* __restrict__ out, int Cin, int Cout, int H, int W,
               int nCoBlk, int ciChunk)
{
    __shared__ float sIn[2][648];   // [buf][sub*324 + iy*18 + ix]
    __shared__ float sWt[2][768];   // [buf][sub*384 + co_l*12 + k] (k<9 used)

    const int tid = threadIdx.x;
    const int bx = blockIdx.x, by = blockIdx.y, bz = blockIdx.z;
    const int co_blk = bz % nCoBlk;
    const int schunk = bz / nCoBlk;
    const int ciBeg = schunk * ciChunk;
    const int ciEnd = min(ciBeg + ciChunk, Cin);
    const int HW = H * W;

    const int co_grp = tid >> 6;          // wave id: 0..3 (wave64)
    const int lane   = tid & 63;
    const int tx = lane & 7, ty = lane >> 3;
    const int x0 = bx * TILE, y0 = by * TILE;

    // ---- precompute staging descriptors (loop-invariant except ci0) ----
    int iLds[3], iG[3], iSub[3]; bool iOk[3];
    int wLds[3], wG[3], wSub[3]; bool wOk[3];
#pragma unroll
    for (int j = 0; j < 3; ++j) {
        int i = tid + j * 256;
        iOk[j] = false; iLds[j] = 0; iG[j] = 0; iSub[j] = 0;
        if (i < 648) {
            int sub = i / 324; int r = i - sub * 324;
            int iy = r / 18;   int ix = r - iy * 18;
            iSub[j] = sub; iLds[j] = sub * 324 + r;
            int y = y0 - 1 + iy, x = x0 - 1 + ix;
            if (y >= 0 && y < H && x >= 0 && x < W) {
                iOk[j] = true; iG[j] = sub * HW + y * W + x;
            }
        }
        wOk[j] = false; wLds[j] = 0; wG[j] = 0; wSub[j] = 0;
        if (i < 576) {
            int sub = i / 288; int r = i - sub * 288;
            int col = r / 9;   int k = r - col * 9;
            wSub[j] = sub; wLds[j] = sub * 384 + col * 12 + k;
            wG[j] = ((co_blk * COB + col) * Cin + sub) * 9 + k;
            wOk[j] = true;
        }
    }

    float4 acc[8];
#pragma unroll
    for (int c = 0; c < 8; ++c) acc[c] = make_float4(0.f, 0.f, 0.f, 0.f);

    const int nSteps = (ciEnd - ciBeg + 1) >> 1;
    float rIn[3], rWt[3];

    // prologue: load + write stage 0
    {
        const int ci0 = ciBeg;
#pragma unroll
        for (int j = 0; j < 3; ++j)
            rIn[j] = (iOk[j] && (ci0 + iSub[j]) < ciEnd) ? in[(size_t)ci0 * HW + iG[j]] : 0.f;
#pragma unroll
        for (int j = 0; j < 3; ++j)
            rWt[j] = (wOk[j] && (ci0 + wSub[j]) < ciEnd) ? wt[(size_t)ci0 * 9 + wG[j]] : 0.f;
#pragma unroll
        for (int j = 0; j < 3; ++j) { if (tid + j * 256 < 648) sIn[0][iLds[j]] = rIn[j]; }
#pragma unroll
        for (int j = 0; j < 3; ++j) { if (tid + j * 256 < 576) sWt[0][wLds[j]] = rWt[j]; }
    }

    for (int t = 0; t < nSteps; ++t) {
        __syncthreads();
        const bool more = (t + 1) < nSteps;
        if (more) {   // issue next stage's global loads; latency hidden by FMAs below
            const int ci0 = ciBeg + 2 * (t + 1);
#pragma unroll
            for (int j = 0; j < 3; ++j)
                rIn[j] = (iOk[j] && (ci0 + iSub[j]) < ciEnd) ? in[(size_t)ci0 * HW + iG[j]] : 0.f;
#pragma unroll
            for (int j = 0; j < 3; ++j)
                rWt[j] = (wOk[j] && (ci0 + wSub[j]) < ciEnd) ? wt[(size_t)ci0 * 9 + wG[j]] : 0.f;
        }
        const int buf = t & 1;
        const float* sI = sIn[buf];
        const float* sW = sWt[buf];
#pragma unroll
        for (int sub = 0; sub < 2; ++sub) {
            float wv[4][4];
            const float* sp = sI + sub * 324 + (2 * ty) * 18 + 2 * tx;
#pragma unroll
            for (int r = 0; r < 4; ++r) {
                float2 a = *(const float2*)(sp + r * 18);
                float2 b = *(const float2*)(sp + r * 18 + 2);
                wv[r][0] = a.x; wv[r][1] = a.y; wv[r][2] = b.x; wv[r][3] = b.y;
            }
#pragma unroll
            for (int c = 0; c < 8; ++c) {
                const float* wp = sW + sub * 384 + (co_grp * 8 + c) * 12;
                float4 w0 = *(const float4*)wp;       // broadcast reads (wave-uniform)
                float4 w1 = *(const float4*)(wp + 4);
                float  w8 = wp[8];
                const float wk[9] = {w0.x, w0.y, w0.z, w0.w, w1.x, w1.y, w1.z, w1.w, w8};
                float* ac = (float*)&acc[c];
#pragma unroll
                for (int py = 0; py < 2; ++py)
#pragma unroll
                for (int px = 0; px < 2; ++px) {
                    float s = ac[py * 2 + px];
#pragma unroll
                    for (int ky = 0; ky < 3; ++ky)
#pragma unroll
                    for (int kx = 0; kx < 3; ++kx)
                        s = fmaf(wv[py + ky][px + kx], wk[ky * 3 + kx], s);
                    ac[py * 2 + px] = s;
                }
            }
        }
        if (more) {   // write next stage into the other buffer (WAR safe: top barrier)
#pragma unroll
            for (int j = 0; j < 3; ++j) { if (tid + j * 256 < 648) sIn[buf ^ 1][iLds[j]] = rIn[j]; }
#pragma unroll
            for (int j = 0; j < 3; ++j) { if (tid + j * 256 < 576) sWt[buf ^ 1][wLds[j]] = rWt[j]; }
        }
    }

    // ---- epilogue ----
    const int co0 = co_blk * COB + co_grp * 8;
    if (PARTIAL) {
        float* op = out + (size_t)schunk * Cout * HW;
        const int y = y0 + 2 * ty, x = x0 + 2 * tx;
#pragma unroll
        for (int c = 0; c < 8; ++c) {
            float* p = op + (size_t)(co0 + c) * HW + y * W + x;
            *(float2*)p       = make_float2(acc[c].x, acc[c].y);
            *(float2*)(p + W) = make_float2(acc[c].z, acc[c].w);
        }
    } else if (POOL) {
        const int Ho = H >> 1, Wo = W >> 1;
        const int yo = (y0 >> 1) + ty, xo = (x0 >> 1) + tx;
#pragma unroll
        for (int c = 0; c < 8; ++c) {
            float m = fmaxf(fmaxf(acc[c].x, acc[c].y), fmaxf(acc[c].z, acc[c].w));
            out[(size_t)(co0 + c) * Ho * Wo + yo * Wo + xo] = fmaxf(m, 0.f);
        }
    } else {
        const int y = y0 + 2 * ty, x = x0 + 2 * tx;
#pragma unroll
        for (int c = 0; c < 8; ++c) {
            float* p = out + (size_t)(co0 + c) * HW + y * W + x;
            *(float2*)p       = make_float2(fmaxf(acc[c].x, 0.f), fmaxf(acc[c].y, 0.f));
            *(float2*)(p + W) = make_float2(fmaxf(acc[c].z, 0.f), fmaxf(acc[c].w, 0.f));
        }
    }
}

__global__ __launch_bounds__(256)
void reduce_relu4_k(const float* __restrict__ P, float* __restrict__ out,
                    int n4, int S, int stride4)
{
    int i = blockIdx.x * 256 + threadIdx.x;
    if (i >= n4) return;
    const float4* p = (const float4*)P;
    float4 a = p[i];
    for (int s = 1; s < S; ++s) {
        float4 b = p[(size_t)i + (size_t)s * stride4];
        a.x += b.x; a.y += b.y; a.z += b.z; a.w += b.w;
    }
    ((float4*)out)[i] = make_float4(fmaxf(a.x, 0.f), fmaxf(a.y, 0.f),
                                    fmaxf(a.z, 0.f), fmaxf(a.w, 0.f));
}

__global__ __launch_bounds__(256)
void reduce_pool_relu_k(const float* __restrict__ P, float* __restrict__ out,
                        int C, int H, int W, int S)
{
    const int Ho = H >> 1, Wo = W >> 1;
    const int M = C * Ho * Wo;
    int i = blockIdx.x * 256 + threadIdx.x;
    if (i >= M) return;
    int co = i / (Ho * Wo);
    int r  = i - co * (Ho * Wo);
    int yo = r / Wo, xo = r - yo * Wo;
    size_t base = (size_t)co * H * W + (size_t)(2 * yo) * W + 2 * xo;
    size_t stride = (size_t)C * H * W;
    float v00 = 0.f, v01 = 0.f, v10 = 0.f, v11 = 0.f;
    for (int s = 0; s < S; ++s) {
        const float* p = P + base + (size_t)s * stride;
        v00 += p[0]; v01 += p[1]; v10 += p[W]; v11 += p[W + 1];
    }
    float m = fmaxf(fmaxf(v00, v01), fmaxf(v10, v11));
    out[i] = fmaxf(m, 0.f);
}

__global__ __launch_bounds__(256)
void gemv_k(const float* __restrict__ Wm, const float* __restrict__ xv,
            float* __restrict__ y, int K)
{
    __shared__ float red[4];
    const int tid = threadIdx.x;
    const float4* row = (const float4*)(Wm + (size_t)blockIdx.x * K);
    const float4* x4  = (const float4*)xv;
    const int K4 = K >> 2;
    float sum = 0.f;
    for (int i = tid; i < K4; i += 256) {
        float4 a = row[i], b = x4[i];
        sum += a.x * b.x + a.y * b.y + a.z * b.z + a.w * b.w;
    }
#pragma unroll
    for (int off = 32; off > 0; off >>= 1) sum += __shfl_down(sum, off, 64);
    if ((tid & 63) == 0) red[tid >> 6] = sum;
    __syncthreads();
    if (tid == 0) y[blockIdx.x] = red[0] + red[1] + red[2] + red[3];
}

static inline void launch_conv(const float* in, const float* wt, float* out,
                               int Cin, int Cout, int H, int W, int S, bool pool,
                               hipStream_t st)
{
    int nCoBlk = Cout / COB;
    int ciChunk = (Cin + S - 1) / S;
    dim3 g(W / TILE, H / TILE, nCoBlk * S);
    if (S > 1)
        conv3x3_k<true, false><<<g, 256, 0, st>>>(in, wt, out, Cin, Cout, H, W, nCoBlk, ciChunk);
    else if (pool)
        conv3x3_k<false, true><<<g, 256, 0, st>>>(in, wt, out, Cin, Cout, H, W, nCoBlk, ciChunk);
    else
        conv3x3_k<false, false><<<g, 256, 0, st>>>(in, wt, out, Cin, Cout, H, W, nCoBlk, ciChunk);
}

static inline void launch_reduce(const float* P, float* out, int C, int H, int W,
                                 int S, bool pool, hipStream_t st)
{
    if (!pool) {
        int n4 = C * H * W / 4;
        reduce_relu4_k<<<(n4 + 255) / 256, 256, 0, st>>>(P, out, n4, S, n4);
    } else {
        int M = C * (H / 2) * (W / 2);
        reduce_pool_relu_k<<<(M + 255) / 256, 256, 0, st>>>(P, out, C, H, W, S);
    }
}

extern "C" void kernel_launch(void* const* d_in, const int* in_sizes, int n_in,
                              void* d_out, int out_size, void* d_ws, size_t ws_size,
                              hipStream_t stream)
{
    (void)in_sizes; (void)n_in; (void)out_size; (void)ws_size;
    const float* x = (const float*)d_in[0];
    // d_in: 0:x 1:H 2:W 3:nTh 4:nTw 5..17:cw1..cw13 18:fw1 19:fw2 20:fw3
    const float* cw[13];
    for (int i = 0; i < 13; ++i) cw[i] = (const float*)d_in[5 + i];
    const float* fw1 = (const float*)d_in[18];
    const float* fw2 = (const float*)d_in[19];
    const float* fw3 = (const float*)d_in[20];
    float* outp = (float*)d_out;

    char* ws = (char*)d_ws;                       // needs ~48.1 MB of d_ws
    float* A  = (float*)(ws);                                  // 16 MB
    float* B  = (float*)(ws + (size_t)16 * 1024 * 1024);       // 16 MB
    float* P  = (float*)(ws + (size_t)32 * 1024 * 1024);       // 16 MB partials
    float* F1 = (float*)(ws + (size_t)48 * 1024 * 1024);       // fc scratch
    float* F2 = F1 + 4096;

    // block 1 (256^2)
    launch_conv(x, cw[0], A, 3,   64, 256, 256, 1, false, stream);
    launch_conv(A, cw[1], B, 64,  64, 256, 256, 1, true,  stream);  // -> 64x128x128
    // block 2 (128^2)
    launch_conv(B, cw[2], A, 64, 128, 128, 128, 1, false, stream);
    launch_conv(A, cw[3], B, 128,128, 128, 128, 1, true,  stream);  // -> 128x64x64
    // block 3 (64^2), ci-split S=4
    launch_conv(B, cw[4], P, 128, 256, 64, 64, 4, false, stream);
    launch_reduce(P, A, 256, 64, 64, 4, false, stream);
    launch_conv(A, cw[5], P, 256, 256, 64, 64, 4, false, stream);
    launch_reduce(P, B, 256, 64, 64, 4, false, stream);
    launch_conv(B, cw[6], P, 256, 256, 64, 64, 4, false, stream);
    launch_reduce(P, A, 256, 64, 64, 4, true, stream);              // -> 256x32x32
    // block 4 (32^2), S=8
    launch_conv(A, cw[7], P, 256, 512, 32, 32, 8, false, stream);
    launch_reduce(P, B, 512, 32, 32, 8, false, stream);
    launch_conv(B, cw[8], P, 512, 512, 32, 32, 8, false, stream);
    launch_reduce(P, A, 512, 32, 32, 8, false, stream);
    launch_conv(A, cw[9], P, 512, 512, 32, 32, 8, false, stream);
    launch_reduce(P, B, 512, 32, 32, 8, true, stream);              // -> 512x16x16
    // block 5 (16^2), S=32
    launch_conv(B, cw[10], P, 512, 512, 16, 16, 32, false, stream);
    launch_reduce(P, A, 512, 16, 16, 32, false, stream);
    launch_conv(A, cw[11], P, 512, 512, 16, 16, 32, false, stream);
    launch_reduce(P, B, 512, 16, 16, 32, false, stream);
    launch_conv(B, cw[12], P, 512, 512, 16, 16, 32, false, stream);
    launch_reduce(P, A, 512, 16, 16, 32, true, stream);             // -> 512x8x8 = h[32768]
    // FC head
    gemv_k<<<4096, 256, 0, stream>>>(fw1, A,  F1, 32768);
    gemv_k<<<4096, 256, 0, stream>>>(fw2, F1, F2, 4096);
    gemv_k<<<1000, 256, 0, stream>>>(fw3, F2, outp, 4096);
}

// Round 2
// 1037.601 us; speedup vs baseline: 1.8419x; 1.8419x over previous
//
#include <hip/hip_runtime.h>
#include <cstddef>

// VGG-16 fwd, batch=1. R2: bf16 MFMA implicit-GEMM convs (16x16x32), fp32 acc.
//  - activations NHWC bf16 (ci contiguous -> 16B frag loads)
//  - weights pre-transformed per launch to [pos][co][ci] bf16
//  - conv block: 64 co x (PR x 16) px, 4 waves, wave tile 64co x (PR/4 * 16)px
//  - ci-split (grid.z) keeps >=256 blocks on small layers; partials reduced
//  - L1 (Cin=3) stays fp32 vector (proven R1 kernel, epilogue -> NHWC bf16)
//  - FC: fp32 GEMV, weight-BW-bound (~100us floor)

typedef __attribute__((ext_vector_type(8))) short short8;
typedef __attribute__((ext_vector_type(4))) float f32x4;

__device__ inline unsigned short f2bf(float f) {
    unsigned int u = __builtin_bit_cast(unsigned int, f);
    u += 0x7FFF + ((u >> 16) & 1);          // RNE
    return (unsigned short)(u >> 16);
}
__device__ inline float bf2f(unsigned short h) {
    unsigned int u = ((unsigned int)h) << 16;
    return __builtin_bit_cast(float, u);
}

// ---------------- weight transform: OIHW fp32 -> [pos][co][ci] bf16 ----------
__global__ void wt_transform_k(const float* __restrict__ w, unsigned short* __restrict__ wt,
                               int Cin, int Cout)
{
    const int co = blockIdx.x, pos = blockIdx.y;
    for (int ci = threadIdx.x; ci < Cin; ci += 64)
        wt[(size_t)(pos * Cout + co) * Cin + ci] = f2bf(w[(size_t)(co * Cin + ci) * 9 + pos]);
}

// ---------------- MFMA conv ----------------
// MODE: 0 = relu+bf16 NHWC   1 = raw bf16 NHWC (pre-pool)   2 = fp32 partial (ci-split)
template<int PR, int MODE>
__global__ __launch_bounds__(256, 2)
void conv_mfma_k(const unsigned short* __restrict__ act,
                 const unsigned short* __restrict__ wt,
                 void* __restrict__ outp,
                 int Cin, int Cout, int H, int W, int chunkCi)
{
    constexpr int NT = PR / 4;                   // N-tiles (rows of 16px) per wave
    constexpr int ICELLS = (PR + 2) * 18;
    __shared__ __align__(16) unsigned short wLds[9 * 64 * 32];   // [pos][co64][ci32]
    __shared__ __align__(16) unsigned short iLds[ICELLS * 32];   // [row][col18][ci32]

    const int tid = threadIdx.x;
    const int lane = tid & 63, wv = tid >> 6;
    const int half = lane >> 4, l15 = lane & 15;
    const int tilesX = W >> 4;
    const int pY = blockIdx.x / tilesX, pX = blockIdx.x - pY * tilesX;
    const int y0 = pY * PR, x0 = pX * 16;
    const int cob = blockIdx.y, s = blockIdx.z;
    const int ciBeg = s * chunkCi, ciEnd = ciBeg + chunkCi;

    f32x4 acc[4][NT];
#pragma unroll
    for (int mt = 0; mt < 4; ++mt)
#pragma unroll
        for (int nt = 0; nt < NT; ++nt) acc[mt][nt] = (f32x4){0.f, 0.f, 0.f, 0.f};

    for (int ci0 = ciBeg; ci0 < ciEnd; ci0 += 32) {
        __syncthreads();
        // ---- stage weights: 9 pos x 64 co x 32 ci (576 cells x 64B, 2304 16B tasks) ----
#pragma unroll
        for (int it = 0; it < 9; ++it) {
            const int idx = it * 256 + tid;
            const int cell = idx >> 2, q = idx & 3;
            const int pos = cell >> 6, co = cell & 63;
            const uint4 v = *(const uint4*)(wt +
                (size_t)(pos * Cout + (cob << 6) + co) * Cin + ci0 + q * 8);
            *(uint4*)&wLds[cell * 32 + q * 8] = v;
        }
        // ---- stage input halo tile: (PR+2) x 18 x 32ci ----
#pragma unroll
        for (int it = 0; it < (ICELLS * 4 + 255) / 256; ++it) {
            const int idx = it * 256 + tid;
            if (idx < ICELLS * 4) {
                const int cell = idx >> 2, q = idx & 3;
                const int r = cell / 18, c = cell - r * 18;
                const int y = y0 - 1 + r, x = x0 - 1 + c;
                uint4 v = {0u, 0u, 0u, 0u};
                if (y >= 0 && y < H && x >= 0 && x < W)
                    v = *(const uint4*)(act + (size_t)(y * W + x) * Cin + ci0 + q * 8);
                *(uint4*)&iLds[cell * 32 + q * 8] = v;
            }
        }
        __syncthreads();
        // ---- 9-position MFMA inner loop ----
#pragma unroll
        for (int ky = 0; ky < 3; ++ky)
#pragma unroll
        for (int kx = 0; kx < 3; ++kx) {
            const int pos = ky * 3 + kx;
            short8 a[4];
#pragma unroll
            for (int mt = 0; mt < 4; ++mt)
                a[mt] = *(const short8*)&wLds[((pos << 6) + (mt << 4) + l15) * 32 + half * 8];
#pragma unroll
            for (int nt = 0; nt < NT; ++nt) {
                const short8 b = *(const short8*)
                    &iLds[((wv * NT + nt + ky) * 18 + l15 + kx) * 32 + half * 8];
#pragma unroll
                for (int mt = 0; mt < 4; ++mt)
                    acc[mt][nt] = __builtin_amdgcn_mfma_f32_16x16x32_bf16(a[mt], b, acc[mt][nt], 0, 0, 0);
            }
        }
    }

    // ---- epilogue: D layout col(lane&15)=pixel-x, row((lane>>4)*4+reg)=co ----
    const int xg = x0 + l15;
#pragma unroll
    for (int mt = 0; mt < 4; ++mt)
#pragma unroll
    for (int nt = 0; nt < NT; ++nt) {
        const int yg = y0 + wv * NT + nt;
        const int co = (cob << 6) + (mt << 4) + half * 4;
        const size_t base = (size_t)(yg * W + xg) * Cout + co;
        if (MODE == 2) {
            float4 v = make_float4(acc[mt][nt][0], acc[mt][nt][1], acc[mt][nt][2], acc[mt][nt][3]);
            *(float4*)((float*)outp + (size_t)s * Cout * H * W + base) = v;
        } else {
            ushort4 u;
            u.x = f2bf(MODE == 0 ? fmaxf(acc[mt][nt][0], 0.f) : acc[mt][nt][0]);
            u.y = f2bf(MODE == 0 ? fmaxf(acc[mt][nt][1], 0.f) : acc[mt][nt][1]);
            u.z = f2bf(MODE == 0 ? fmaxf(acc[mt][nt][2], 0.f) : acc[mt][nt][2]);
            u.w = f2bf(MODE == 0 ? fmaxf(acc[mt][nt][3], 0.f) : acc[mt][nt][3]);
            *(ushort4*)((unsigned short*)outp + base) = u;
        }
    }
}

// ---------------- L1: fp32 vector conv (Cin=3), epilogue -> NHWC bf16+relu ----
#define TILE 16
#define COB  32
__global__ __launch_bounds__(256)
void conv1_k(const float* __restrict__ in, const float* __restrict__ wt,
             unsigned short* __restrict__ out)
{
    const int Cin = 3, H = 256, W = 256, HW = H * W;
    __shared__ float sIn[2][648];
    __shared__ float sWt[2][768];

    const int tid = threadIdx.x;
    const int bx = blockIdx.x, by = blockIdx.y, co_blk = blockIdx.z;
    const int co_grp = tid >> 6;
    const int lane = tid & 63;
    const int tx = lane & 7, ty = lane >> 3;
    const int x0 = bx * TILE, y0 = by * TILE;

    int iLdsI[3], iG[3], iSub[3]; bool iOk[3];
    int wLdsI[3], wG[3], wSub[3]; bool wOk[3];
#pragma unroll
    for (int j = 0; j < 3; ++j) {
        int i = tid + j * 256;
        iOk[j] = false; iLdsI[j] = 0; iG[j] = 0; iSub[j] = 0;
        if (i < 648) {
            int sub = i / 324; int r = i - sub * 324;
            int iy = r / 18;   int ix = r - iy * 18;
            iSub[j] = sub; iLdsI[j] = sub * 324 + r;
            int y = y0 - 1 + iy, x = x0 - 1 + ix;
            if (y >= 0 && y < H && x >= 0 && x < W) { iOk[j] = true; iG[j] = sub * HW + y * W + x; }
        }
        wOk[j] = false; wLdsI[j] = 0; wG[j] = 0; wSub[j] = 0;
        if (i < 576) {
            int sub = i / 288; int r = i - sub * 288;
            int col = r / 9;   int k = r - col * 9;
            wSub[j] = sub; wLdsI[j] = sub * 384 + col * 12 + k;
            wG[j] = ((co_blk * COB + col) * Cin + sub) * 9 + k;
            wOk[j] = true;
        }
    }

    float4 acc[8];
#pragma unroll
    for (int c = 0; c < 8; ++c) acc[c] = make_float4(0.f, 0.f, 0.f, 0.f);

    const int nSteps = 2;   // ci pairs (0,1),(2,-)
    float rIn[3], rWt[3];
    {
#pragma unroll
        for (int j = 0; j < 3; ++j)
            rIn[j] = (iOk[j] && iSub[j] < 3) ? in[iG[j]] : 0.f;
#pragma unroll
        for (int j = 0; j < 3; ++j)
            rWt[j] = (wOk[j] && wSub[j] < 3) ? wt[wG[j]] : 0.f;
#pragma unroll
        for (int j = 0; j < 3; ++j) { if (tid + j * 256 < 648) sIn[0][iLdsI[j]] = rIn[j]; }
#pragma unroll
        for (int j = 0; j < 3; ++j) { if (tid + j * 256 < 576) sWt[0][wLdsI[j]] = rWt[j]; }
    }

    for (int t = 0; t < nSteps; ++t) {
        __syncthreads();
        const bool more = (t + 1) < nSteps;
        if (more) {
            const int ci0 = 2;
#pragma unroll
            for (int j = 0; j < 3; ++j)
                rIn[j] = (iOk[j] && (ci0 + iSub[j]) < 3) ? in[(size_t)ci0 * HW + iG[j]] : 0.f;
#pragma unroll
            for (int j = 0; j < 3; ++j)
                rWt[j] = (wOk[j] && (ci0 + wSub[j]) < 3) ? wt[(size_t)ci0 * 9 + wG[j]] : 0.f;
        }
        const int buf = t & 1;
        const float* sI = sIn[buf];
        const float* sW = sWt[buf];
#pragma unroll
        for (int sub = 0; sub < 2; ++sub) {
            float wv[4][4];
            const float* sp = sI + sub * 324 + (2 * ty) * 18 + 2 * tx;
#pragma unroll
            for (int r = 0; r < 4; ++r) {
                float2 a = *(const float2*)(sp + r * 18);
                float2 b = *(const float2*)(sp + r * 18 + 2);
                wv[r][0] = a.x; wv[r][1] = a.y; wv[r][2] = b.x; wv[r][3] = b.y;
            }
#pragma unroll
            for (int c = 0; c < 8; ++c) {
                const float* wp = sW + sub * 384 + (co_grp * 8 + c) * 12;
                float4 w0 = *(const float4*)wp;
                float4 w1 = *(const float4*)(wp + 4);
                float  w8 = wp[8];
                const float wk[9] = {w0.x, w0.y, w0.z, w0.w, w1.x, w1.y, w1.z, w1.w, w8};
                float* ac = (float*)&acc[c];
#pragma unroll
                for (int py = 0; py < 2; ++py)
#pragma unroll
                for (int px = 0; px < 2; ++px) {
                    float sacc = ac[py * 2 + px];
#pragma unroll
                    for (int kk = 0; kk < 9; ++kk)
                        sacc = fmaf(wv[py + kk / 3][px + kk % 3], wk[kk], sacc);
                    ac[py * 2 + px] = sacc;
                }
            }
        }
        if (more) {
#pragma unroll
            for (int j = 0; j < 3; ++j) { if (tid + j * 256 < 648) sIn[buf ^ 1][iLdsI[j]] = rIn[j]; }
#pragma unroll
            for (int j = 0; j < 3; ++j) { if (tid + j * 256 < 576) sWt[buf ^ 1][wLdsI[j]] = rWt[j]; }
        }
    }

    const int co0 = co_blk * COB + co_grp * 8;   // 8 consecutive co
#pragma unroll
    for (int py = 0; py < 2; ++py)
#pragma unroll
    for (int px = 0; px < 2; ++px) {
        const int y = y0 + 2 * ty + py, x = x0 + 2 * tx + px;
        unsigned short u8[8];
#pragma unroll
        for (int c = 0; c < 8; ++c)
            u8[c] = f2bf(fmaxf(((const float*)&acc[c])[py * 2 + px], 0.f));
        *(uint4*)(out + (size_t)(y * W + x) * 64 + co0) = *(uint4*)u8;
    }
}

// ---------------- aux kernels ----------------
// 2x2 maxpool + relu on raw bf16 NHWC -> bf16 NHWC
__global__ __launch_bounds__(256)
void pool_cvt_k(const unsigned short* __restrict__ P, unsigned short* __restrict__ out,
                int C, int H, int W)
{
    const int C8 = C >> 3, Wo = W >> 1, Ho = H >> 1;
    const int n = Ho * Wo * C8;
    int i = blockIdx.x * 256 + threadIdx.x;
    if (i >= n) return;
    const int c8 = i % C8, p = i / C8;
    const int yo = p / Wo, xo = p - yo * Wo;
    const size_t b = (size_t)(2 * yo * W + 2 * xo) * C + c8 * 8;
    uint4 a0 = *(const uint4*)(P + b);
    uint4 a1 = *(const uint4*)(P + b + C);
    uint4 a2 = *(const uint4*)(P + b + (size_t)W * C);
    uint4 a3 = *(const uint4*)(P + b + (size_t)W * C + C);
    const unsigned short* s0 = (const unsigned short*)&a0;
    const unsigned short* s1 = (const unsigned short*)&a1;
    const unsigned short* s2 = (const unsigned short*)&a2;
    const unsigned short* s3 = (const unsigned short*)&a3;
    unsigned short u8[8];
#pragma unroll
    for (int k = 0; k < 8; ++k) {
        float m = fmaxf(fmaxf(bf2f(s0[k]), bf2f(s1[k])), fmaxf(bf2f(s2[k]), bf2f(s3[k])));
        u8[k] = f2bf(fmaxf(m, 0.f));
    }
    *(uint4*)(out + (size_t)p * C + c8 * 8) = *(uint4*)u8;
}

// sum S fp32 partials + relu -> bf16 NHWC
__global__ __launch_bounds__(256)
void reduce_cvt_k(const float* __restrict__ P, unsigned short* __restrict__ out,
                  int n4, int S)
{
    int i = blockIdx.x * 256 + threadIdx.x;
    if (i >= n4) return;
    const float4* p4 = (const float4*)P;
    float4 a = p4[i];
    for (int s = 1; s < S; ++s) {
        float4 b = p4[(size_t)i + (size_t)s * n4];
        a.x += b.x; a.y += b.y; a.z += b.z; a.w += b.w;
    }
    ushort4 u;
    u.x = f2bf(fmaxf(a.x, 0.f)); u.y = f2bf(fmaxf(a.y, 0.f));
    u.z = f2bf(fmaxf(a.z, 0.f)); u.w = f2bf(fmaxf(a.w, 0.f));
    *(ushort4*)(out + (size_t)i * 4) = u;
}

// sum S fp32 partials, 2x2 maxpool, relu -> bf16 NHWC
__global__ __launch_bounds__(256)
void reduce_pool_cvt_k(const float* __restrict__ P, unsigned short* __restrict__ out,
                       int C, int H, int W, int S)
{
    const int C4 = C >> 2, Wo = W >> 1, Ho = H >> 1;
    const int n = Ho * Wo * C4;
    int i = blockIdx.x * 256 + threadIdx.x;
    if (i >= n) return;
    const int c4 = i % C4, p = i / C4;
    const int yo = p / Wo, xo = p - yo * Wo;
    const size_t CHW = (size_t)C * H * W;
    const size_t b = (size_t)(2 * yo * W + 2 * xo) * C + c4 * 4;
    float4 v[4] = {{0,0,0,0},{0,0,0,0},{0,0,0,0},{0,0,0,0}};
    for (int s = 0; s < S; ++s) {
        const float* ps = P + s * CHW;
        float4 t0 = *(const float4*)(ps + b);
        float4 t1 = *(const float4*)(ps + b + C);
        float4 t2 = *(const float4*)(ps + b + (size_t)W * C);
        float4 t3 = *(const float4*)(ps + b + (size_t)W * C + C);
        v[0].x += t0.x; v[0].y += t0.y; v[0].z += t0.z; v[0].w += t0.w;
        v[1].x += t1.x; v[1].y += t1.y; v[1].z += t1.z; v[1].w += t1.w;
        v[2].x += t2.x; v[2].y += t2.y; v[2].z += t2.z; v[2].w += t2.w;
        v[3].x += t3.x; v[3].y += t3.y; v[3].z += t3.z; v[3].w += t3.w;
    }
    ushort4 u;
    u.x = f2bf(fmaxf(fmaxf(fmaxf(v[0].x, v[1].x), fmaxf(v[2].x, v[3].x)), 0.f));
    u.y = f2bf(fmaxf(fmaxf(fmaxf(v[0].y, v[1].y), fmaxf(v[2].y, v[3].y)), 0.f));
    u.z = f2bf(fmaxf(fmaxf(fmaxf(v[0].z, v[1].z), fmaxf(v[2].z, v[3].z)), 0.f));
    u.w = f2bf(fmaxf(fmaxf(fmaxf(v[0].w, v[1].w), fmaxf(v[2].w, v[3].w)), 0.f));
    *(ushort4*)(out + (size_t)p * C + c4 * 4) = u;
}

// L13: sum 16 partials, pool, relu -> fp32 NCHW flatten order
__global__ __launch_bounds__(256)
void reduce_pool_f32_k(const float* __restrict__ P, float* __restrict__ out,
                       int C, int H, int W, int S)
{
    const int Wo = W >> 1, Ho = H >> 1;
    const int n = Ho * Wo * C;
    int i = blockIdx.x * 256 + threadIdx.x;
    if (i >= n) return;
    const int c = i % C, p = i / C;
    const int yo = p / Wo, xo = p - yo * Wo;
    const size_t CHW = (size_t)C * H * W;
    float v0 = 0.f, v1 = 0.f, v2 = 0.f, v3 = 0.f;
    const size_t b = (size_t)(2 * yo * W + 2 * xo) * C + c;
    for (int s = 0; s < S; ++s) {
        const float* ps = P + s * CHW;
        v0 += ps[b]; v1 += ps[b + C]; v2 += ps[b + (size_t)W * C]; v3 += ps[b + (size_t)W * C + C];
    }
    out[(size_t)c * (Ho * Wo) + p] = fmaxf(fmaxf(fmaxf(v0, v1), fmaxf(v2, v3)), 0.f);
}

// ---------------- FC GEMV (fp32, weight-BW-bound) ----------------
__global__ __launch_bounds__(256)
void gemv_k(const float* __restrict__ Wm, const float* __restrict__ xv,
            float* __restrict__ y, int K)
{
    __shared__ float red[4];
    const int tid = threadIdx.x;
    const float4* row = (const float4*)(Wm + (size_t)blockIdx.x * K);
    const float4* x4  = (const float4*)xv;
    const int K4 = K >> 2;
    float sum = 0.f;
    for (int i = tid; i < K4; i += 256) {
        float4 a = row[i], b = x4[i];
        sum += a.x * b.x + a.y * b.y + a.z * b.z + a.w * b.w;
    }
#pragma unroll
    for (int off = 32; off > 0; off >>= 1) sum += __shfl_down(sum, off, 64);
    if ((tid & 63) == 0) red[tid >> 6] = sum;
    __syncthreads();
    if (tid == 0) y[blockIdx.x] = red[0] + red[1] + red[2] + red[3];
}

// ---------------- launcher ----------------
extern "C" void kernel_launch(void* const* d_in, const int* in_sizes, int n_in,
                              void* d_out, int out_size, void* d_ws, size_t ws_size,
                              hipStream_t stream)
{
    (void)in_sizes; (void)n_in; (void)out_size; (void)ws_size;
    const float* x = (const float*)d_in[0];
    const float* cw[13];
    for (int i = 0; i < 13; ++i) cw[i] = (const float*)d_in[5 + i];
    const float* fw1 = (const float*)d_in[18];
    const float* fw2 = (const float*)d_in[19];
    const float* fw3 = (const float*)d_in[20];
    float* outp = (float*)d_out;

    // layers 2..13 (index 0..11 here)
    static const int CIN[12]  = {64, 64, 128, 128, 256, 256, 256, 512, 512, 512, 512, 512};
    static const int COUT[12] = {64, 128, 128, 256, 256, 256, 512, 512, 512, 512, 512, 512};

    char* ws = (char*)d_ws;
    size_t wOff[12]; size_t o = 0;
    for (int i = 0; i < 12; ++i) { wOff[i] = o; o += (size_t)9 * COUT[i] * CIN[i]; }
    unsigned short* WT = (unsigned short*)ws;               // 29.4 MB bf16
    size_t ao = (o * 2 + 255) & ~(size_t)255;
    unsigned short* bA = (unsigned short*)(ws + ao);        // 8.39 MB
    unsigned short* bB = (unsigned short*)(ws + ao + 8388608);
    char* Pr = ws + ao + 2 * 8388608;                       // 8.39 MB partial/raw
    unsigned short* Pu = (unsigned short*)Pr;
    float* Pf = (float*)Pr;
    float* fcIn = (float*)bA;                               // L13 result (128 KB)
    float* F1 = (float*)bB;
    float* F2 = F1 + 4096;

    // weight transforms
    for (int i = 0; i < 12; ++i)
        wt_transform_k<<<dim3(COUT[i], 9), 64, 0, stream>>>(cw[i + 1], WT + wOff[i], CIN[i], COUT[i]);

    // L1: fp32 vector conv 3->64 @256^2, out NHWC bf16
    conv1_k<<<dim3(16, 16, 2), 256, 0, stream>>>(x, cw[0], bA);

    // L2: 64->64 @256^2, raw bf16 -> pool -> 128^2
    conv_mfma_k<16, 1><<<dim3(256, 1, 1), 256, 0, stream>>>(bA, WT + wOff[0], Pu, 64, 64, 256, 256, 64);
    pool_cvt_k<<<(128 * 128 * 8 + 255) / 256, 256, 0, stream>>>(Pu, bB, 64, 256, 256);
    // L3: 64->128 @128^2
    conv_mfma_k<8, 0><<<dim3(128, 2, 1), 256, 0, stream>>>(bB, WT + wOff[1], bA, 64, 128, 128, 128, 64);
    // L4: 128->128 @128^2, raw -> pool -> 64^2
    conv_mfma_k<8, 1><<<dim3(128, 2, 1), 256, 0, stream>>>(bA, WT + wOff[2], Pu, 128, 128, 128, 128, 128);
    pool_cvt_k<<<(64 * 64 * 16 + 255) / 256, 256, 0, stream>>>(Pu, bB, 128, 128, 128);
    // L5: 128->256 @64^2, S=2
    conv_mfma_k<8, 2><<<dim3(32, 4, 2), 256, 0, stream>>>(bB, WT + wOff[3], Pf, 128, 256, 64, 64, 64);
    reduce_cvt_k<<<(262144 + 255) / 256, 256, 0, stream>>>(Pf, bA, 262144, 2);
    // L6: 256->256 @64^2, S=2
    conv_mfma_k<8, 2><<<dim3(32, 4, 2), 256, 0, stream>>>(bA, WT + wOff[4], Pf, 256, 256, 64, 64, 128);
    reduce_cvt_k<<<(262144 + 255) / 256, 256, 0, stream>>>(Pf, bB, 262144, 2);
    // L7: 256->256 @64^2, S=2, pool -> 32^2
    conv_mfma_k<8, 2><<<dim3(32, 4, 2), 256, 0, stream>>>(bB, WT + wOff[5], Pf, 256, 256, 64, 64, 128);
    reduce_pool_cvt_k<<<(65536 + 255) / 256, 256, 0, stream>>>(Pf, bA, 256, 64, 64, 2);
    // L8: 256->512 @32^2, S=4
    conv_mfma_k<8, 2><<<dim3(8, 8, 4), 256, 0, stream>>>(bA, WT + wOff[6], Pf, 256, 512, 32, 32, 64);
    reduce_cvt_k<<<(131072 + 255) / 256, 256, 0, stream>>>(Pf, bB, 131072, 4);
    // L9: 512->512 @32^2, S=4
    conv_mfma_k<8, 2><<<dim3(8, 8, 4), 256, 0, stream>>>(bB, WT + wOff[7], Pf, 512, 512, 32, 32, 128);
    reduce_cvt_k<<<(131072 + 255) / 256, 256, 0, stream>>>(Pf, bA, 131072, 4);
    // L10: 512->512 @32^2, S=4, pool -> 16^2
    conv_mfma_k<8, 2><<<dim3(8, 8, 4), 256, 0, stream>>>(bA, WT + wOff[8], Pf, 512, 512, 32, 32, 128);
    reduce_pool_cvt_k<<<(32768 + 255) / 256, 256, 0, stream>>>(Pf, bB, 512, 32, 32, 4);
    // L11: 512->512 @16^2, S=16
    conv_mfma_k<8, 2><<<dim3(2, 8, 16), 256, 0, stream>>>(bB, WT + wOff[9], Pf, 512, 512, 16, 16, 32);
    reduce_cvt_k<<<(32768 + 255) / 256, 256, 0, stream>>>(Pf, bA, 32768, 16);
    // L12
    conv_mfma_k<8, 2><<<dim3(2, 8, 16), 256, 0, stream>>>(bA, WT + wOff[10], Pf, 512, 512, 16, 16, 32);
    reduce_cvt_k<<<(32768 + 255) / 256, 256, 0, stream>>>(Pf, bB, 32768, 16);
    // L13: S=16, pool -> fp32 NCHW flatten [512][8][8]
    conv_mfma_k<8, 2><<<dim3(2, 8, 16), 256, 0, stream>>>(bB, WT + wOff[11], Pf, 512, 512, 16, 16, 32);
    reduce_pool_f32_k<<<(32768 + 255) / 256, 256, 0, stream>>>(Pf, fcIn, 512, 16, 16, 16);

    // FC head (fp32, HBM-bound on weights)
    gemv_k<<<4096, 256, 0, stream>>>(fw1, fcIn, F1, 32768);
    gemv_k<<<4096, 256, 0, stream>>>(fw2, F1, F2, 4096);
    gemv_k<<<1000, 256, 0, stream>>>(fw3, F2, outp, 4096);
}